// Round 15
// baseline (304.233 us; speedup 1.0000x reference)
//
#include <hip/hip_runtime.h>
#include <hip/hip_bf16.h>

#define NNODES 50000
#define NEDGES 800000
#define NGRAPHS 32
#define NSPEC 10
#define CC 32
#define RH 64
#define NB 8

#define EBLK 128
#define NCHUNK (NEDGES / EBLK)
#define GSTR 136   // Gt row stride (shorts)
#define YSTR 136   // Yt row stride (shorts, bf16)
#define YOFF 6528  // Yt offset inside smem_u (shorts) = 13,056B (after Gt's 48*136)
#define ASTR 72    // act row stride in shorts
#define RBSTR 40   // rbA row stride in shorts
#define SCAN_N 53248

typedef __bf16 bf16x8 __attribute__((ext_vector_type(8)));
typedef __bf16 bf16x2 __attribute__((ext_vector_type(2)));
typedef float f32x4 __attribute__((ext_vector_type(4)));

#if __has_builtin(__builtin_amdgcn_fdot2_f32_bf16)
#define HAVE_DOT2 1
#endif

__device__ __forceinline__ unsigned pack2bf(float a, float b) {
    return (unsigned)__bfloat16_as_ushort(__float2bfloat16(a)) |
           ((unsigned)__bfloat16_as_ushort(__float2bfloat16(b)) << 16);
}
__device__ __forceinline__ float silu(float x) {
    return x * __builtin_amdgcn_rcpf(1.f + __expf(-x));
}
__device__ __forceinline__ float dot2bf(unsigned g, unsigned y, float acc) {
#ifdef HAVE_DOT2
    return __builtin_amdgcn_fdot2_f32_bf16(__builtin_bit_cast(bf16x2, g),
                                           __builtin_bit_cast(bf16x2, y), acc, false);
#else
    float r = fmaf(__uint_as_float(g << 16), __uint_as_float(y << 16), acc);
    return fmaf(__uint_as_float(g & 0xffff0000u), __uint_as_float(y & 0xffff0000u), r);
#endif
}

// ---------------- fused prelude: histogram(+rank) + species + weight transpose ----------------
__global__ __launch_bounds__(256) void prep_hist_kernel(
    const float* __restrict__ attrs, const int* __restrict__ eidx,
    const float* __restrict__ rW1, const float* __restrict__ rb1,
    const float* __restrict__ rW2, const float* __restrict__ rW3,
    int* __restrict__ counts, int* __restrict__ rank, int* __restrict__ species,
    __hip_bfloat16* __restrict__ W1T, __hip_bfloat16* __restrict__ W2T,
    __hip_bfloat16* __restrict__ W3T) {
    __shared__ float at[256 * NSPEC];
    const int tid = threadIdx.x;
    int g = blockIdx.x * 256 + tid;
    if (g < NEDGES) rank[g] = atomicAdd(&counts[eidx[NEDGES + g]], 1);
    const int nbase = blockIdx.x * 256;
    if (nbase < NNODES) {
        for (int i = tid; i < 256 * NSPEC; i += 256) {
            int idx = nbase * NSPEC + i;
            at[i] = (idx < NNODES * NSPEC) ? attrs[idx] : 0.f;
        }
        __syncthreads();
        if (g < NNODES) {
            float acc = 0.f;
#pragma unroll
            for (int s = 0; s < NSPEC; ++s) acc += at[tid * NSPEC + s] * (float)s;
            species[g] = (int)(acc + 0.5f);
        }
    }
    if (g < 64 * 32) {  // W1T[col][k]: k<8 = rW1[k][col], k==8 = rb1[col], else 0
        int c = g >> 5, k = g & 31;
        float v = (k < 8) ? rW1[k * 64 + c] : ((k == 8) ? rb1[c] : 0.f);
        W1T[g] = __float2bfloat16(v);
    }
    if (g < 64 * 64) {
        int c = g >> 6, k = g & 63;
        W2T[g] = __float2bfloat16(rW2[k * 64 + c]);
    }
    if (g < 96 * 64) {
        int c = g >> 6, k = g & 63;
        W3T[g] = __float2bfloat16(rW3[k * 96 + c]);
    }
}

// ---------------- scan: single block, int4, CH=52; also zeroes out ----------------
__global__ __launch_bounds__(1024) void scan_kernel(const int* __restrict__ counts,
                                                    int* __restrict__ offsets,
                                                    float* __restrict__ out) {
    __shared__ int sums[1024];
    const int t = threadIdx.x;
    if (t < NGRAPHS) out[t] = 0.f;
    const int base = t * 52;
    int loc[52];
    int s = 0;
#pragma unroll
    for (int i = 0; i < 13; ++i) {
        int4 v = *(const int4*)&counts[base + i * 4];
        loc[i * 4 + 0] = v.x; loc[i * 4 + 1] = v.y;
        loc[i * 4 + 2] = v.z; loc[i * 4 + 3] = v.w;
        s += v.x + v.y + v.z + v.w;
    }
    sums[t] = s;
    __syncthreads();
    for (int off = 1; off < 1024; off <<= 1) {
        int add = (t >= off) ? sums[t - off] : 0;
        __syncthreads();
        sums[t] += add;
        __syncthreads();
    }
    int run = sums[t] - s;
#pragma unroll
    for (int i = 0; i < 13; ++i) {
        int4 o;
        o.x = run; run += loc[i * 4 + 0];
        o.y = run; run += loc[i * 4 + 1];
        o.z = run; run += loc[i * 4 + 2];
        o.w = run; run += loc[i * 4 + 3];
        *(int4*)&offsets[base + i * 4] = o;
    }
}

// ---------------- scatter: atomic-free (precomputed rank) ----------------
__global__ __launch_bounds__(256) void scatter_kernel(const int* __restrict__ eidx,
                                                      const int* __restrict__ offsets,
                                                      const int* __restrict__ rank,
                                                      int* __restrict__ perm) {
    int e = blockIdx.x * 256 + threadIdx.x;
    if (e >= NEDGES) return;
    int rcv = eidx[NEDGES + e];
    perm[offsets[rcv] + rank[e]] = e;
}

// ---------------- zero only chunk-boundary A rows ----------------
__global__ __launch_bounds__(576) void zero_bounds_kernel(const int* __restrict__ perm,
                                                          const int* __restrict__ eidx,
                                                          float* __restrict__ A) {
    const int c = blockIdx.x;
    const int t = threadIdx.x;
    const int slot = (t < 288) ? c * EBLK : (c * EBLK + EBLK - 1);
    const int e = perm[slot];
    const int rcv = eidx[NEDGES + e];
    A[(size_t)rcv * (CC * 9) + (t % 288)] = 0.f;
}

// ---------------- segment flush helper ----------------
__device__ __forceinline__ void flushseg(float* __restrict__ A, int node, int cur,
                                         int nseg, int cbase, int j, bool wr8,
                                         float aj, float a8) {
    float* Ap = A + (size_t)node * (CC * 9) + cbase * 9;
    if (cur == 0 || cur == nseg - 1) {
        atomicAdd(Ap + j, aj);
        if (wr8) atomicAdd(Ap + 8, a8);
    } else {
        Ap[j] = aj;
        if (wr8) Ap[8] = a8;
    }
}

// ---------------- phase-2 + Gt-store (templated on column half P) ----------------
template <int P>
__device__ __forceinline__ void pass_store_reduce(
    const f32x4 (&acc3)[4][6], const int (&sp_r)[4][4],
    __hip_bfloat16* Gt, const __hip_bfloat16* Yt, const float* WembLds,
    const unsigned short* rcv_s, const unsigned long long* bal_s,
    float* __restrict__ A, int tid, int w, int lnlo, int q4) {
    // ---- store Gt[s][e] = R * h_sender, packed 4-wide along e
#pragma unroll
    for (int nti = 0; nti < 3; ++nti) {
        const int nt = P * 3 + nti;
        const int col = nt * 16 + lnlo;
        const int cch = col / 3;
        const int s = nti * 16 + lnlo;
#pragma unroll
        for (int mt = 0; mt < 4; ++mt) {
            const float f0 = acc3[mt][nt][0] * WembLds[sp_r[mt][0] * 32 + cch];
            const float f1 = acc3[mt][nt][1] * WembLds[sp_r[mt][1] * 32 + cch];
            const float f2 = acc3[mt][nt][2] * WembLds[sp_r[mt][2] * 32 + cch];
            const float f3 = acc3[mt][nt][3] * WembLds[sp_r[mt][3] * 32 + cch];
            uint2 pk;
            pk.x = pack2bf(f0, f1);
            pk.y = pack2bf(f2, f3);
            *(uint2*)&Gt[s * GSTR + w * 64 + mt * 16 + q4 * 4] = pk;
        }
    }
    __syncthreads();

    // ---- segmented reduce; headless chunks use pairwise dot2, head chunks scalar
    {
        const int c = tid >> 3;
        const int j = tid & 7;
        const bool m8 = (j == 7);
        const int l_j = (j == 0) ? 0 : ((j < 4) ? 1 : 2);
        const uint4* gj = (const uint4*)(Gt + (3 * c + l_j) * GSTR);
        const uint4* yj = (const uint4*)(Yt + j * YSTR);
        const uint4* y8p = (const uint4*)(Yt + 8 * YSTR);
        const unsigned long long b0 = bal_s[0], b1 = bal_s[1];
        const int nseg = __popcll(b0) + __popcll(b1);
        const int cbase = P * 16 + c;

        float aj = 0.f, a8 = 0.f;
        int cur = 0;
        int node = rcv_s[0];

        for (int ch = 0; ch < 16; ++ch) {
            unsigned msk = (unsigned)(((ch < 8) ? (b0 >> (ch * 8)) : (b1 >> ((ch - 8) * 8))) & 0xffull);
            if (ch == 0) msk &= ~1u;
            const uint4 gv = gj[ch];
            const uint4 yv = yj[ch];
            uint4 yv8 = {0, 0, 0, 0};
            if (m8) yv8 = y8p[ch];
            const unsigned gw[4] = {gv.x, gv.y, gv.z, gv.w};
            const unsigned yw[4] = {yv.x, yv.y, yv.z, yv.w};
            const unsigned yw8[4] = {yv8.x, yv8.y, yv8.z, yv8.w};

            if (msk == 0) {  // block-uniform: no segment heads in this chunk
#pragma unroll
                for (int p = 0; p < 4; ++p) {
                    aj = dot2bf(gw[p], yw[p], aj);
                    if (m8) a8 = dot2bf(gw[p], yw8[p], a8);
                }
            } else {
#pragma unroll
                for (int i = 0; i < 8; ++i) {
                    if (msk & (1u << i)) {
                        flushseg(A, node, cur, nseg, cbase, j, m8, aj, a8);
                        aj = 0.f; a8 = 0.f; ++cur;
                        node = rcv_s[ch * 8 + i];
                    }
                    const unsigned gu = gw[i >> 1], yu = yw[i >> 1];
                    const float gf = __uint_as_float((i & 1) ? (gu & 0xffff0000u) : (gu << 16));
                    const float yf = __uint_as_float((i & 1) ? (yu & 0xffff0000u) : (yu << 16));
                    aj = fmaf(gf, yf, aj);
                    if (m8) {
                        const unsigned zu = yw8[i >> 1];
                        const float zf = __uint_as_float((i & 1) ? (zu & 0xffff0000u) : (zu << 16));
                        a8 = fmaf(gf, zf, a8);
                    }
                }
            }
        }
        flushseg(A, node, cur, nseg, cbase, j, m8, aj, a8);
    }
    __syncthreads();  // protect Gt (and Yt region in pass 0->1 handoff: Yt untouched)
}

// ---------------- edge kernel: full-MFMA MLP + segmented scatter ----------------
// LDS budget: smem_u 18,432 + Wemb 1,280 + rb2L 256 + rcv 256 + spec 128 + bal 16
//           = 20,368 B  ->  8 blocks/CU (Yt lives INSIDE smem_u at +13,056B,
//             written after layer-3 when act is dead; Gt only uses 13,056B).
__global__ __launch_bounds__(EBLK, 4) void edge_kernel(
    const float* __restrict__ pos, const float* __restrict__ shifts,
    const int* __restrict__ eidx, const int* __restrict__ perm,
    const __hip_bfloat16* __restrict__ W1T, const __hip_bfloat16* __restrict__ W2T,
    const __hip_bfloat16* __restrict__ W3T, const float* __restrict__ rb2,
    const int* __restrict__ species, const float* __restrict__ Wemb,
    float* __restrict__ A) {
    __shared__ __align__(16) short smem_u[128 * ASTR];
    __shared__ __align__(16) float WembLds[NSPEC * CC];
    __shared__ __align__(16) float rb2L[RH];
    __shared__ __align__(16) unsigned short rcv_s[EBLK];
    __shared__ __align__(16) unsigned char spec_s[EBLK];
    __shared__ __align__(16) unsigned long long bal_s[2];

    __hip_bfloat16* act = (__hip_bfloat16*)smem_u;
    __hip_bfloat16* Gt = (__hip_bfloat16*)smem_u;
    __hip_bfloat16* rbA = (__hip_bfloat16*)smem_u;
    __hip_bfloat16* Yt = (__hip_bfloat16*)(smem_u + YOFF);  // 13,056B offset

    const int tid = threadIdx.x;
    const int lane = tid & 63;
    const int w = tid >> 6;
    const int lnlo = lane & 15;
    const int q4 = lane >> 4;

    const int slot = blockIdx.x * EBLK + tid;
    const int eid = perm[slot];
    const int snd = eidx[eid];
    const int rcv = eidx[NEDGES + eid];

    const float vx = pos[rcv * 3 + 0] - pos[snd * 3 + 0] + shifts[eid * 3 + 0];
    const float vy = pos[rcv * 3 + 1] - pos[snd * 3 + 1] + shifts[eid * 3 + 1];
    const float vz = pos[rcv * 3 + 2] - pos[snd * 3 + 2] + shifts[eid * 3 + 2];
    const float r = sqrtf(vx * vx + vy * vy + vz * vz);
    const float safe_r = fmaxf(r, 1e-9f);
    const float rinv = 1.f / safe_r;
    const float ux = vx * rinv, uy = vy * rinv, uz = vz * rinv;

    // ---- metadata -> LDS (Yt deferred until after layer 3)
    {
        rcv_s[tid] = (unsigned short)rcv;
        spec_s[tid] = (unsigned char)species[snd];
        for (int i = tid; i < NSPEC * CC; i += EBLK) WembLds[i] = Wemb[i];
        if (tid < RH) rb2L[tid] = rb2[tid];
    }

    // ---- radial basis -> rbA row (sin recurrence)
    {
        const float u = r * 0.2f;
        const float u2 = u * u;
        const float u6 = u2 * u2 * u2;
        const float u7 = u6 * u;
        const float u8v = u7 * u;
        float fcut = 1.f - 28.f * u6 + 48.f * u7 - 21.f * u8v;
        fcut = (u < 1.f) ? fcut : 0.f;
        const float pref = 0.632455532f * rinv * fcut;
        const float x = 0.628318530718f * safe_r;
        float s1, c1;
        __sincosf(x, &s1, &c1);
        const float tc = 2.f * c1;
        float rb[NB];
        float sp = 0.f, sc = s1;
        rb[0] = sc * pref;
#pragma unroll
        for (int k = 1; k < NB; ++k) {
            const float sn = tc * sc - sp;
            sp = sc; sc = sn;
            rb[k] = sc * pref;
        }
        uint4 v0, v1;
        v0.x = pack2bf(rb[0], rb[1]); v0.y = pack2bf(rb[2], rb[3]);
        v0.z = pack2bf(rb[4], rb[5]); v0.w = pack2bf(rb[6], rb[7]);
        v1.x = 0x3F80u; v1.y = 0u; v1.z = 0u; v1.w = 0u;
        uint4 vz4 = {0u, 0u, 0u, 0u};
        *(uint4*)&rbA[tid * RBSTR + 0] = v0;
        *(uint4*)&rbA[tid * RBSTR + 8] = v1;
        *(uint4*)&rbA[tid * RBSTR + 16] = vz4;
        *(uint4*)&rbA[tid * RBSTR + 24] = vz4;
    }

    __syncthreads();  // rcv_s + rbA visible cross-wave
    {
        const bool head = (tid == 0) || (rcv_s[tid] != rcv_s[tid - 1]);
        const unsigned long long bal = __ballot(head);
        if ((tid & 63) == 0) bal_s[tid >> 6] = bal;
    }

    // ---- layer 1 (SWAPPED): C = [ch][edge]
    f32x4 acc1[4][4];
#pragma unroll
    for (int jt = 0; jt < 4; ++jt)
#pragma unroll
        for (int et = 0; et < 4; ++et) acc1[jt][et] = (f32x4){0.f, 0.f, 0.f, 0.f};
    {
        bf16x8 wf[4], af[4];
#pragma unroll
        for (int jt = 0; jt < 4; ++jt)
            wf[jt] = *(const bf16x8*)&W1T[(jt * 16 + lnlo) * 32 + q4 * 8];
#pragma unroll
        for (int et = 0; et < 4; ++et)
            af[et] = *(const bf16x8*)&rbA[(w * 64 + et * 16 + lnlo) * RBSTR + q4 * 8];
        __syncthreads();
#pragma unroll
        for (int jt = 0; jt < 4; ++jt)
#pragma unroll
            for (int et = 0; et < 4; ++et)
                acc1[jt][et] = __builtin_amdgcn_mfma_f32_16x16x32_bf16(
                    wf[jt], af[et], acc1[jt][et], 0, 0, 0);
    }

    // ---- silu(acc1) -> act[e][ch], packed b64
#pragma unroll
    for (int jt = 0; jt < 4; ++jt) {
        const int ch0 = jt * 16 + q4 * 4;
#pragma unroll
        for (int et = 0; et < 4; ++et) {
            const int e = w * 64 + et * 16 + lnlo;
            uint2 pk;
            pk.x = pack2bf(silu(acc1[jt][et][0]), silu(acc1[jt][et][1]));
            pk.y = pack2bf(silu(acc1[jt][et][2]), silu(acc1[jt][et][3]));
            *(uint2*)&act[e * ASTR + ch0] = pk;
        }
    }
    __syncthreads();

    // ---- layer 2 (SWAPPED)
    f32x4 acc2[4][4];
#pragma unroll
    for (int jt = 0; jt < 4; ++jt)
#pragma unroll
        for (int et = 0; et < 4; ++et) acc2[jt][et] = (f32x4){0.f, 0.f, 0.f, 0.f};
    {
        bf16x8 wf[4][2], af[4][2];
#pragma unroll
        for (int jt = 0; jt < 4; ++jt)
#pragma unroll
            for (int kk = 0; kk < 2; ++kk)
                wf[jt][kk] = *(const bf16x8*)&W2T[(jt * 16 + lnlo) * 64 + kk * 32 + q4 * 8];
#pragma unroll
        for (int et = 0; et < 4; ++et)
#pragma unroll
            for (int kk = 0; kk < 2; ++kk)
                af[et][kk] = *(const bf16x8*)&act[(w * 64 + et * 16 + lnlo) * ASTR + kk * 32 + q4 * 8];
#pragma unroll
        for (int kk = 0; kk < 2; ++kk)
#pragma unroll
            for (int jt = 0; jt < 4; ++jt)
#pragma unroll
                for (int et = 0; et < 4; ++et)
                    acc2[jt][et] = __builtin_amdgcn_mfma_f32_16x16x32_bf16(
                        wf[jt][kk], af[et][kk], acc2[jt][et], 0, 0, 0);
    }
    __syncthreads();

    // ---- silu(acc2 + rb2) -> act2, packed b64
#pragma unroll
    for (int jt = 0; jt < 4; ++jt) {
        const int ch0 = jt * 16 + q4 * 4;
        const float4 bv = *(const float4*)&rb2L[ch0];
#pragma unroll
        for (int et = 0; et < 4; ++et) {
            const int e = w * 64 + et * 16 + lnlo;
            uint2 pk;
            pk.x = pack2bf(silu(acc2[jt][et][0] + bv.x), silu(acc2[jt][et][1] + bv.y));
            pk.y = pack2bf(silu(acc2[jt][et][2] + bv.z), silu(acc2[jt][et][3] + bv.w));
            *(uint2*)&act[e * ASTR + ch0] = pk;
        }
    }
    __syncthreads();

    // ---- layer 3 (UNSWAPPED): C = [edge][ch]
    f32x4 acc3[4][6];
#pragma unroll
    for (int mt = 0; mt < 4; ++mt)
#pragma unroll
        for (int nt = 0; nt < 6; ++nt) acc3[mt][nt] = (f32x4){0.f, 0.f, 0.f, 0.f};
    {
        bf16x8 a3[4][2], b3[6][2];
#pragma unroll
        for (int mt = 0; mt < 4; ++mt)
#pragma unroll
            for (int kk = 0; kk < 2; ++kk)
                a3[mt][kk] = *(const bf16x8*)&act[(w * 64 + mt * 16 + lnlo) * ASTR + kk * 32 + q4 * 8];
#pragma unroll
        for (int nt = 0; nt < 6; ++nt)
#pragma unroll
            for (int kk = 0; kk < 2; ++kk)
                b3[nt][kk] = *(const bf16x8*)&W3T[(nt * 16 + lnlo) * 64 + kk * 32 + q4 * 8];
#pragma unroll
        for (int kk = 0; kk < 2; ++kk)
#pragma unroll
            for (int mt = 0; mt < 4; ++mt)
#pragma unroll
                for (int nt = 0; nt < 6; ++nt)
                    acc3[mt][nt] = __builtin_amdgcn_mfma_f32_16x16x32_bf16(
                        a3[mt][kk], b3[nt][kk], acc3[mt][nt], 0, 0, 0);
    }
    __syncthreads();  // act fully dead; Gt + Yt regions now writable

    // ---- write Yt (deferred; ux/uy/uz still live) -- visible after pass<0>'s barrier
    {
        const float s3 = 1.7320508075688772f;
        const float s15 = 3.872983346207417f;
        const float s15h = 1.9364916731037085f;
        const float s5h = 1.118033988749895f;
        Yt[0 * YSTR + tid] = __float2bfloat16(1.f);
        Yt[1 * YSTR + tid] = __float2bfloat16(s3 * ux);
        Yt[2 * YSTR + tid] = __float2bfloat16(s3 * uy);
        Yt[3 * YSTR + tid] = __float2bfloat16(s3 * uz);
        Yt[4 * YSTR + tid] = __float2bfloat16(s15 * ux * uy);
        Yt[5 * YSTR + tid] = __float2bfloat16(s15 * uy * uz);
        Yt[6 * YSTR + tid] = __float2bfloat16(s5h * (3.f * uz * uz - 1.f));
        Yt[7 * YSTR + tid] = __float2bfloat16(s15 * ux * uz);
        Yt[8 * YSTR + tid] = __float2bfloat16(s15h * (ux * ux - uy * uy));
    }

    int sp_r[4][4];
#pragma unroll
    for (int mt = 0; mt < 4; ++mt)
#pragma unroll
        for (int rr = 0; rr < 4; ++rr)
            sp_r[mt][rr] = (int)spec_s[w * 64 + mt * 16 + q4 * 4 + rr];

    pass_store_reduce<0>(acc3, sp_r, Gt, Yt, WembLds, rcv_s, bal_s, A, tid, w, lnlo, q4);
    pass_store_reduce<1>(acc3, sp_r, Gt, Yt, WembLds, rcv_s, bal_s, A, tid, w, lnlo, q4);
}

// ---------------- node kernel: A -> A2 -> B -> node_e, fused per-graph reduce ----------------
__global__ __launch_bounds__(256) void node_kernel(
    const float* __restrict__ A, const float* __restrict__ Wmix,
    const float* __restrict__ wquad, const float* __restrict__ Wread,
    const float* __restrict__ attrs, const float* __restrict__ ae,
    const int* __restrict__ batch, const int* __restrict__ counts,
    float* __restrict__ out) {
    __shared__ float Ald[8][CC * 9];
    __shared__ float ne_s[8];
    __shared__ int g_s[8];
    const int t = threadIdx.x;
    const int ln = t >> 5;
    const int d = t & 31;
    const int n = blockIdx.x * 8 + ln;

    const float sc = (counts[n] != 0) ? (1.f / 16.f) : 0.f;
    const float* Arow = A + (size_t)n * (CC * 9);
#pragma unroll
    for (int i = 0; i < 9; ++i) Ald[ln][d + 32 * i] = Arow[d + 32 * i] * sc;
    __syncthreads();

    float A2[9];
#pragma unroll
    for (int m = 0; m < 9; ++m) {
        const int l = (m == 0) ? 0 : ((m < 4) ? 1 : 2);
        float acc = 0.f;
#pragma unroll
        for (int cch = 0; cch < CC; ++cch)
            acc = fmaf(Wmix[(l * CC + cch) * CC + d], Ald[ln][cch * 9 + m], acc);
        A2[m] = acc;
    }

    const float q0 = wquad[0], q1 = wquad[1], q2 = wquad[2];
    const float n0 = A2[0] * A2[0];
    const float n1 = A2[1] * A2[1] + A2[2] * A2[2] + A2[3] * A2[3];
    const float n2 = A2[4] * A2[4] + A2[5] * A2[5] + A2[6] * A2[6] + A2[7] * A2[7] + A2[8] * A2[8];
    const float B = A2[0] + n0 * q0 + n1 * q1 + n2 * q2;

    float v = B * Wread[d];
#pragma unroll
    for (int off = 16; off; off >>= 1) v += __shfl_xor(v, off, 32);

    if (d == 0) {
        float ne = v;
#pragma unroll
        for (int s = 0; s < NSPEC; ++s) ne += attrs[n * NSPEC + s] * ae[s];
        ne_s[ln] = ne;
        g_s[ln] = batch[n];
    }
    __syncthreads();
    if (t == 0) {
        float acc = ne_s[0];
        int g = g_s[0];
#pragma unroll
        for (int i = 1; i < 8; ++i) {
            if (g_s[i] == g) acc += ne_s[i];
            else { atomicAdd(&out[g], acc); g = g_s[i]; acc = ne_s[i]; }
        }
        atomicAdd(&out[g], acc);
    }
}

extern "C" void kernel_launch(void* const* d_in, const int* in_sizes, int n_in,
                              void* d_out, int out_size, void* d_ws, size_t ws_size,
                              hipStream_t stream) {
    const float* attrs  = (const float*)d_in[0];
    const float* pos    = (const float*)d_in[1];
    const float* shifts = (const float*)d_in[2];
    const float* Wemb   = (const float*)d_in[3];
    const float* rW1    = (const float*)d_in[4];
    const float* rb1    = (const float*)d_in[5];
    const float* rW2    = (const float*)d_in[6];
    const float* rb2    = (const float*)d_in[7];
    const float* rW3    = (const float*)d_in[8];
    const float* Wmix   = (const float*)d_in[9];
    const float* wquad  = (const float*)d_in[10];
    const float* Wread  = (const float*)d_in[11];
    const float* ae     = (const float*)d_in[12];
    const int* eidx     = (const int*)d_in[13];
    const int* batch    = (const int*)d_in[14];
    float* out = (float*)d_out;

    char* wsp = (char*)d_ws;
    float* A      = (float*)wsp;  wsp += (size_t)NNODES * CC * 9 * 4;  // 57.6 MB
    int* rank     = (int*)A;      // alias: dead after scatter; boundary rows re-zeroed
    int* perm     = (int*)wsp;    wsp += (size_t)NEDGES * 4;           // 3.2 MB
    int* offsets  = (int*)wsp;    wsp += (size_t)SCAN_N * 4;
    int* counts   = (int*)wsp;    wsp += (size_t)SCAN_N * 4;
    int* species  = (int*)wsp;    wsp += (size_t)NNODES * 4;
    __hip_bfloat16* W1T = (__hip_bfloat16*)wsp; wsp += 64 * 32 * 2;
    __hip_bfloat16* W2T = (__hip_bfloat16*)wsp; wsp += 64 * 64 * 2;
    __hip_bfloat16* W3T = (__hip_bfloat16*)wsp; wsp += 96 * 64 * 2;

    hipMemsetAsync(counts, 0, (size_t)SCAN_N * sizeof(int), stream);

    prep_hist_kernel<<<NEDGES / 256, 256, 0, stream>>>(attrs, eidx, rW1, rb1, rW2, rW3,
                                                       counts, rank, species, W1T, W2T, W3T);
    scan_kernel<<<1, 1024, 0, stream>>>(counts, offsets, out);
    scatter_kernel<<<NEDGES / 256, 256, 0, stream>>>(eidx, offsets, rank, perm);
    zero_bounds_kernel<<<NCHUNK, 576, 0, stream>>>(perm, eidx, A);

    edge_kernel<<<NCHUNK, EBLK, 0, stream>>>(pos, shifts, eidx, perm,
                                             W1T, W2T, W3T, rb2, species, Wemb, A);
    node_kernel<<<NNODES / 8, 256, 0, stream>>>(A, Wmix, wquad, Wread, attrs, ae, batch,
                                                counts, out);
}

// Round 18
// 294.432 us; speedup vs baseline: 1.0333x; 1.0333x over previous
//
#include <hip/hip_runtime.h>
#include <hip/hip_bf16.h>

#define NNODES 50000
#define NEDGES 800000
#define NGRAPHS 32
#define NSPEC 10
#define CC 32
#define RH 64
#define NB 8

#define EBLK 128
#define NCHUNK (NEDGES / EBLK)
#define GSTR 136   // Gt row stride (shorts)
#define YSTR 136   // Yt row stride (shorts, bf16)
#define ASTR 72    // act row stride in shorts
#define RBSTR 40   // rbA row stride in shorts
#define SCAN_N 53248

typedef __bf16 bf16x8 __attribute__((ext_vector_type(8)));
typedef __bf16 bf16x2 __attribute__((ext_vector_type(2)));
typedef float f32x4 __attribute__((ext_vector_type(4)));

#if __has_builtin(__builtin_amdgcn_fdot2_f32_bf16)
#define HAVE_DOT2 1
#endif

__device__ __forceinline__ unsigned pack2bf(float a, float b) {
    return (unsigned)__bfloat16_as_ushort(__float2bfloat16(a)) |
           ((unsigned)__bfloat16_as_ushort(__float2bfloat16(b)) << 16);
}
__device__ __forceinline__ float silu(float x) {
    return x * __builtin_amdgcn_rcpf(1.f + __expf(-x));  // approx rcp: ~1e-7 rel err
}
__device__ __forceinline__ float dot2bf(unsigned g, unsigned y, float acc) {
#ifdef HAVE_DOT2
    return __builtin_amdgcn_fdot2_f32_bf16(__builtin_bit_cast(bf16x2, g),
                                           __builtin_bit_cast(bf16x2, y), acc, false);
#else
    float r = fmaf(__uint_as_float(g << 16), __uint_as_float(y << 16), acc);
    return fmaf(__uint_as_float(g & 0xffff0000u), __uint_as_float(y & 0xffff0000u), r);
#endif
}

// ---------------- fused prelude: histogram(+rank) + species + weight transpose ----------------
__global__ __launch_bounds__(256) void prep_hist_kernel(
    const float* __restrict__ attrs, const int* __restrict__ eidx,
    const float* __restrict__ rW1, const float* __restrict__ rb1,
    const float* __restrict__ rW2, const float* __restrict__ rW3,
    int* __restrict__ counts, int* __restrict__ rank, int* __restrict__ species,
    __hip_bfloat16* __restrict__ W1T, __hip_bfloat16* __restrict__ W2T,
    __hip_bfloat16* __restrict__ W3T) {
    __shared__ float at[256 * NSPEC];
    const int tid = threadIdx.x;
    int g = blockIdx.x * 256 + tid;
    if (g < NEDGES) rank[g] = atomicAdd(&counts[eidx[NEDGES + g]], 1);
    const int nbase = blockIdx.x * 256;
    if (nbase < NNODES) {
        for (int i = tid; i < 256 * NSPEC; i += 256) {
            int idx = nbase * NSPEC + i;
            at[i] = (idx < NNODES * NSPEC) ? attrs[idx] : 0.f;
        }
        __syncthreads();
        if (g < NNODES) {
            float acc = 0.f;
#pragma unroll
            for (int s = 0; s < NSPEC; ++s) acc += at[tid * NSPEC + s] * (float)s;
            species[g] = (int)(acc + 0.5f);
        }
    }
    if (g < 64 * 32) {  // W1T[col][k]: k<8 = rW1[k][col], k==8 = rb1[col], else 0
        int c = g >> 5, k = g & 31;
        float v = (k < 8) ? rW1[k * 64 + c] : ((k == 8) ? rb1[c] : 0.f);
        W1T[g] = __float2bfloat16(v);
    }
    if (g < 64 * 64) {
        int c = g >> 6, k = g & 63;
        W2T[g] = __float2bfloat16(rW2[k * 64 + c]);
    }
    if (g < 96 * 64) {
        int c = g >> 6, k = g & 63;
        W3T[g] = __float2bfloat16(rW3[k * 96 + c]);
    }
}

// ---------------- scan: single block, int4, CH=52; also zeroes out ----------------
__global__ __launch_bounds__(1024) void scan_kernel(const int* __restrict__ counts,
                                                    int* __restrict__ offsets,
                                                    float* __restrict__ out) {
    __shared__ int sums[1024];
    const int t = threadIdx.x;
    if (t < NGRAPHS) out[t] = 0.f;
    const int base = t * 52;
    int loc[52];
    int s = 0;
#pragma unroll
    for (int i = 0; i < 13; ++i) {
        int4 v = *(const int4*)&counts[base + i * 4];
        loc[i * 4 + 0] = v.x; loc[i * 4 + 1] = v.y;
        loc[i * 4 + 2] = v.z; loc[i * 4 + 3] = v.w;
        s += v.x + v.y + v.z + v.w;
    }
    sums[t] = s;
    __syncthreads();
    for (int off = 1; off < 1024; off <<= 1) {
        int add = (t >= off) ? sums[t - off] : 0;
        __syncthreads();
        sums[t] += add;
        __syncthreads();
    }
    int run = sums[t] - s;
#pragma unroll
    for (int i = 0; i < 13; ++i) {
        int4 o;
        o.x = run; run += loc[i * 4 + 0];
        o.y = run; run += loc[i * 4 + 1];
        o.z = run; run += loc[i * 4 + 2];
        o.w = run; run += loc[i * 4 + 3];
        *(int4*)&offsets[base + i * 4] = o;
    }
}

// ---------------- scatter: atomic-free (precomputed rank) ----------------
__global__ __launch_bounds__(256) void scatter_kernel(const int* __restrict__ eidx,
                                                      const int* __restrict__ offsets,
                                                      const int* __restrict__ rank,
                                                      int* __restrict__ perm) {
    int e = blockIdx.x * 256 + threadIdx.x;
    if (e >= NEDGES) return;
    int rcv = eidx[NEDGES + e];
    perm[offsets[rcv] + rank[e]] = e;
}

// ---------------- zero only chunk-boundary A rows (AFTER scatter: rank alias dead) ----------------
__global__ __launch_bounds__(576) void zero_bounds_kernel(const int* __restrict__ perm,
                                                          const int* __restrict__ eidx,
                                                          float* __restrict__ A) {
    const int c = blockIdx.x;
    const int t = threadIdx.x;
    const int slot = (t < 288) ? c * EBLK : (c * EBLK + EBLK - 1);
    const int e = perm[slot];
    const int rcv = eidx[NEDGES + e];
    A[(size_t)rcv * (CC * 9) + (t % 288)] = 0.f;
}

// ---------------- segment flush helper ----------------
__device__ __forceinline__ void flushseg(float* __restrict__ A, int node, int cur,
                                         int nseg, int cbase, int j, bool wr8,
                                         float aj, float a8) {
    float* Ap = A + (size_t)node * (CC * 9) + cbase * 9;
    if (cur == 0 || cur == nseg - 1) {
        atomicAdd(Ap + j, aj);
        if (wr8) atomicAdd(Ap + 8, a8);
    } else {
        Ap[j] = aj;
        if (wr8) Ap[8] = a8;
    }
}

// ---------------- phase-2 + Gt-store (templated on column half P) ----------------
template <int P>
__device__ __forceinline__ void pass_store_reduce(
    const f32x4 (&acc3)[4][6], const int (&sp_r)[4][4],
    __hip_bfloat16* Gt, const __hip_bfloat16* Yt, const float* WembLds,
    const unsigned short* rcv_s, const unsigned long long* bal_s,
    float* __restrict__ A, int tid, int w, int lnlo, int q4) {
    // ---- store Gt[s][e] = R * h_sender, packed 4-wide along e
#pragma unroll
    for (int nti = 0; nti < 3; ++nti) {
        const int nt = P * 3 + nti;
        const int col = nt * 16 + lnlo;
        const int cch = col / 3;
        const int s = nti * 16 + lnlo;
#pragma unroll
        for (int mt = 0; mt < 4; ++mt) {
            const float f0 = acc3[mt][nt][0] * WembLds[sp_r[mt][0] * 32 + cch];
            const float f1 = acc3[mt][nt][1] * WembLds[sp_r[mt][1] * 32 + cch];
            const float f2 = acc3[mt][nt][2] * WembLds[sp_r[mt][2] * 32 + cch];
            const float f3 = acc3[mt][nt][3] * WembLds[sp_r[mt][3] * 32 + cch];
            uint2 pk;
            pk.x = pack2bf(f0, f1);
            pk.y = pack2bf(f2, f3);
            *(uint2*)&Gt[s * GSTR + w * 64 + mt * 16 + q4 * 4] = pk;
        }
    }
    __syncthreads();

    // ---- segmented reduce; headless chunks use pairwise dot2, head chunks scalar
    {
        const int c = tid >> 3;
        const int j = tid & 7;
        const bool m8 = (j == 7);
        const int l_j = (j == 0) ? 0 : ((j < 4) ? 1 : 2);
        const uint4* gj = (const uint4*)(Gt + (3 * c + l_j) * GSTR);
        const uint4* yj = (const uint4*)(Yt + j * YSTR);
        const uint4* y8p = (const uint4*)(Yt + 8 * YSTR);
        const unsigned long long b0 = bal_s[0], b1 = bal_s[1];
        const int nseg = __popcll(b0) + __popcll(b1);
        const int cbase = P * 16 + c;

        float aj = 0.f, a8 = 0.f;
        int cur = 0;
        int node = rcv_s[0];

        for (int ch = 0; ch < 16; ++ch) {
            unsigned msk = (unsigned)(((ch < 8) ? (b0 >> (ch * 8)) : (b1 >> ((ch - 8) * 8))) & 0xffull);
            if (ch == 0) msk &= ~1u;
            const uint4 gv = gj[ch];
            const uint4 yv = yj[ch];
            uint4 yv8 = {0, 0, 0, 0};
            if (m8) yv8 = y8p[ch];
            const unsigned gw[4] = {gv.x, gv.y, gv.z, gv.w};
            const unsigned yw[4] = {yv.x, yv.y, yv.z, yv.w};
            const unsigned yw8[4] = {yv8.x, yv8.y, yv8.z, yv8.w};

            if (msk == 0) {  // block-uniform: no segment heads in this chunk
#pragma unroll
                for (int p = 0; p < 4; ++p) {
                    aj = dot2bf(gw[p], yw[p], aj);
                    if (m8) a8 = dot2bf(gw[p], yw8[p], a8);
                }
            } else {
#pragma unroll
                for (int i = 0; i < 8; ++i) {
                    if (msk & (1u << i)) {
                        flushseg(A, node, cur, nseg, cbase, j, m8, aj, a8);
                        aj = 0.f; a8 = 0.f; ++cur;
                        node = rcv_s[ch * 8 + i];
                    }
                    const unsigned gu = gw[i >> 1], yu = yw[i >> 1];
                    const float gf = __uint_as_float((i & 1) ? (gu & 0xffff0000u) : (gu << 16));
                    const float yf = __uint_as_float((i & 1) ? (yu & 0xffff0000u) : (yu << 16));
                    aj = fmaf(gf, yf, aj);
                    if (m8) {
                        const unsigned zu = yw8[i >> 1];
                        const float zf = __uint_as_float((i & 1) ? (zu & 0xffff0000u) : (zu << 16));
                        a8 = fmaf(gf, zf, a8);
                    }
                }
            }
        }
        flushseg(A, node, cur, nseg, cbase, j, m8, aj, a8);
    }
    __syncthreads();  // protect Gt before next pass overwrites
}

// ---------------- edge kernel: full-MFMA MLP + segmented scatter ----------------
__global__ __launch_bounds__(EBLK, 3) void edge_kernel(
    const float* __restrict__ pos, const float* __restrict__ shifts,
    const int* __restrict__ eidx, const int* __restrict__ perm,
    const __hip_bfloat16* __restrict__ W1T, const __hip_bfloat16* __restrict__ W2T,
    const __hip_bfloat16* __restrict__ W3T, const float* __restrict__ rb2,
    const int* __restrict__ species, const float* __restrict__ Wemb,
    float* __restrict__ A) {
    __shared__ __align__(16) short smem_u[128 * ASTR];
    __shared__ __align__(16) __hip_bfloat16 Yt[9 * YSTR + 4];
    __shared__ float WembLds[NSPEC * CC];
    __shared__ float rb2L[RH];
    __shared__ unsigned short rcv_s[EBLK];
    __shared__ unsigned char spec_s[EBLK];
    __shared__ unsigned long long bal_s[2];

    __hip_bfloat16* act = (__hip_bfloat16*)smem_u;
    __hip_bfloat16* Gt = (__hip_bfloat16*)smem_u;
    __hip_bfloat16* rbA = (__hip_bfloat16*)smem_u;

    const int tid = threadIdx.x;
    const int lane = tid & 63;
    const int w = tid >> 6;
    const int lnlo = lane & 15;
    const int q4 = lane >> 4;

    const int slot = blockIdx.x * EBLK + tid;
    const int eid = perm[slot];
    const int snd = eidx[eid];
    const int rcv = eidx[NEDGES + eid];

    const float vx = pos[rcv * 3 + 0] - pos[snd * 3 + 0] + shifts[eid * 3 + 0];
    const float vy = pos[rcv * 3 + 1] - pos[snd * 3 + 1] + shifts[eid * 3 + 1];
    const float vz = pos[rcv * 3 + 2] - pos[snd * 3 + 2] + shifts[eid * 3 + 2];
    const float r = sqrtf(vx * vx + vy * vy + vz * vz);
    const float safe_r = fmaxf(r, 1e-9f);
    const float rinv = 1.f / safe_r;
    const float ux = vx * rinv, uy = vy * rinv, uz = vz * rinv;

    // ---- spherical harmonics (bf16) + metadata -> LDS
    {
        const float s3 = 1.7320508075688772f;
        const float s15 = 3.872983346207417f;
        const float s15h = 1.9364916731037085f;
        const float s5h = 1.118033988749895f;
        Yt[0 * YSTR + tid] = __float2bfloat16(1.f);
        Yt[1 * YSTR + tid] = __float2bfloat16(s3 * ux);
        Yt[2 * YSTR + tid] = __float2bfloat16(s3 * uy);
        Yt[3 * YSTR + tid] = __float2bfloat16(s3 * uz);
        Yt[4 * YSTR + tid] = __float2bfloat16(s15 * ux * uy);
        Yt[5 * YSTR + tid] = __float2bfloat16(s15 * uy * uz);
        Yt[6 * YSTR + tid] = __float2bfloat16(s5h * (3.f * uz * uz - 1.f));
        Yt[7 * YSTR + tid] = __float2bfloat16(s15 * ux * uz);
        Yt[8 * YSTR + tid] = __float2bfloat16(s15h * (ux * ux - uy * uy));
        rcv_s[tid] = (unsigned short)rcv;
        spec_s[tid] = (unsigned char)species[snd];
        for (int i = tid; i < NSPEC * CC; i += EBLK) WembLds[i] = Wemb[i];
        if (tid < RH) rb2L[tid] = rb2[tid];
    }

    // ---- radial basis -> rbA row (sin recurrence)
    {
        const float u = r * 0.2f;
        const float u2 = u * u;
        const float u6 = u2 * u2 * u2;
        const float u7 = u6 * u;
        const float u8v = u7 * u;
        float fcut = 1.f - 28.f * u6 + 48.f * u7 - 21.f * u8v;
        fcut = (u < 1.f) ? fcut : 0.f;
        const float pref = 0.632455532f * rinv * fcut;
        const float x = 0.628318530718f * safe_r;
        float s1, c1;
        __sincosf(x, &s1, &c1);
        const float tc = 2.f * c1;
        float rb[NB];
        float sp = 0.f, sc = s1;
        rb[0] = sc * pref;
#pragma unroll
        for (int k = 1; k < NB; ++k) {
            const float sn = tc * sc - sp;
            sp = sc; sc = sn;
            rb[k] = sc * pref;
        }
        uint4 v0, v1;
        v0.x = pack2bf(rb[0], rb[1]); v0.y = pack2bf(rb[2], rb[3]);
        v0.z = pack2bf(rb[4], rb[5]); v0.w = pack2bf(rb[6], rb[7]);
        v1.x = 0x3F80u; v1.y = 0u; v1.z = 0u; v1.w = 0u;
        uint4 vz4 = {0u, 0u, 0u, 0u};
        *(uint4*)&rbA[tid * RBSTR + 0] = v0;
        *(uint4*)&rbA[tid * RBSTR + 8] = v1;
        *(uint4*)&rbA[tid * RBSTR + 16] = vz4;
        *(uint4*)&rbA[tid * RBSTR + 24] = vz4;
    }

    __syncthreads();
    {
        const bool head = (tid == 0) || (rcv_s[tid] != rcv_s[tid - 1]);
        const unsigned long long bal = __ballot(head);
        if ((tid & 63) == 0) bal_s[tid >> 6] = bal;
    }

    // ---- layer 1 (SWAPPED): C = [ch][edge]
    f32x4 acc1[4][4];
#pragma unroll
    for (int jt = 0; jt < 4; ++jt)
#pragma unroll
        for (int et = 0; et < 4; ++et) acc1[jt][et] = (f32x4){0.f, 0.f, 0.f, 0.f};
    {
        bf16x8 wf[4], af[4];
#pragma unroll
        for (int jt = 0; jt < 4; ++jt)
            wf[jt] = *(const bf16x8*)&W1T[(jt * 16 + lnlo) * 32 + q4 * 8];
#pragma unroll
        for (int et = 0; et < 4; ++et)
            af[et] = *(const bf16x8*)&rbA[(w * 64 + et * 16 + lnlo) * RBSTR + q4 * 8];
        __syncthreads();
#pragma unroll
        for (int jt = 0; jt < 4; ++jt)
#pragma unroll
            for (int et = 0; et < 4; ++et)
                acc1[jt][et] = __builtin_amdgcn_mfma_f32_16x16x32_bf16(
                    wf[jt], af[et], acc1[jt][et], 0, 0, 0);
    }

    // ---- silu(acc1) -> act[e][ch], packed b64
#pragma unroll
    for (int jt = 0; jt < 4; ++jt) {
        const int ch0 = jt * 16 + q4 * 4;
#pragma unroll
        for (int et = 0; et < 4; ++et) {
            const int e = w * 64 + et * 16 + lnlo;
            uint2 pk;
            pk.x = pack2bf(silu(acc1[jt][et][0]), silu(acc1[jt][et][1]));
            pk.y = pack2bf(silu(acc1[jt][et][2]), silu(acc1[jt][et][3]));
            *(uint2*)&act[e * ASTR + ch0] = pk;
        }
    }
    __syncthreads();

    // ---- layer 2 (SWAPPED)
    f32x4 acc2[4][4];
#pragma unroll
    for (int jt = 0; jt < 4; ++jt)
#pragma unroll
        for (int et = 0; et < 4; ++et) acc2[jt][et] = (f32x4){0.f, 0.f, 0.f, 0.f};
    {
        bf16x8 wf[4][2], af[4][2];
#pragma unroll
        for (int jt = 0; jt < 4; ++jt)
#pragma unroll
            for (int kk = 0; kk < 2; ++kk)
                wf[jt][kk] = *(const bf16x8*)&W2T[(jt * 16 + lnlo) * 64 + kk * 32 + q4 * 8];
#pragma unroll
        for (int et = 0; et < 4; ++et)
#pragma unroll
            for (int kk = 0; kk < 2; ++kk)
                af[et][kk] = *(const bf16x8*)&act[(w * 64 + et * 16 + lnlo) * ASTR + kk * 32 + q4 * 8];
#pragma unroll
        for (int kk = 0; kk < 2; ++kk)
#pragma unroll
            for (int jt = 0; jt < 4; ++jt)
#pragma unroll
                for (int et = 0; et < 4; ++et)
                    acc2[jt][et] = __builtin_amdgcn_mfma_f32_16x16x32_bf16(
                        wf[jt][kk], af[et][kk], acc2[jt][et], 0, 0, 0);
    }
    __syncthreads();

    // ---- silu(acc2 + rb2) -> act2, packed b64
#pragma unroll
    for (int jt = 0; jt < 4; ++jt) {
        const int ch0 = jt * 16 + q4 * 4;
        const float4 bv = *(const float4*)&rb2L[ch0];
#pragma unroll
        for (int et = 0; et < 4; ++et) {
            const int e = w * 64 + et * 16 + lnlo;
            uint2 pk;
            pk.x = pack2bf(silu(acc2[jt][et][0] + bv.x), silu(acc2[jt][et][1] + bv.y));
            pk.y = pack2bf(silu(acc2[jt][et][2] + bv.z), silu(acc2[jt][et][3] + bv.w));
            *(uint2*)&act[e * ASTR + ch0] = pk;
        }
    }
    __syncthreads();

    // ---- layer 3 (UNSWAPPED): C = [edge][ch]
    f32x4 acc3[4][6];
#pragma unroll
    for (int mt = 0; mt < 4; ++mt)
#pragma unroll
        for (int nt = 0; nt < 6; ++nt) acc3[mt][nt] = (f32x4){0.f, 0.f, 0.f, 0.f};
    {
        bf16x8 a3[4][2], b3[6][2];
#pragma unroll
        for (int mt = 0; mt < 4; ++mt)
#pragma unroll
            for (int kk = 0; kk < 2; ++kk)
                a3[mt][kk] = *(const bf16x8*)&act[(w * 64 + mt * 16 + lnlo) * ASTR + kk * 32 + q4 * 8];
#pragma unroll
        for (int nt = 0; nt < 6; ++nt)
#pragma unroll
            for (int kk = 0; kk < 2; ++kk)
                b3[nt][kk] = *(const bf16x8*)&W3T[(nt * 16 + lnlo) * 64 + kk * 32 + q4 * 8];
#pragma unroll
        for (int kk = 0; kk < 2; ++kk)
#pragma unroll
            for (int mt = 0; mt < 4; ++mt)
#pragma unroll
                for (int nt = 0; nt < 6; ++nt)
                    acc3[mt][nt] = __builtin_amdgcn_mfma_f32_16x16x32_bf16(
                        a3[mt][kk], b3[nt][kk], acc3[mt][nt], 0, 0, 0);
    }
    __syncthreads();

    int sp_r[4][4];
#pragma unroll
    for (int mt = 0; mt < 4; ++mt)
#pragma unroll
        for (int rr = 0; rr < 4; ++rr)
            sp_r[mt][rr] = (int)spec_s[w * 64 + mt * 16 + q4 * 4 + rr];

    pass_store_reduce<0>(acc3, sp_r, Gt, Yt, WembLds, rcv_s, bal_s, A, tid, w, lnlo, q4);
    pass_store_reduce<1>(acc3, sp_r, Gt, Yt, WembLds, rcv_s, bal_s, A, tid, w, lnlo, q4);
}

// ---------------- node kernel: A -> A2 -> B -> node_e, fused per-graph reduce ----------------
__global__ __launch_bounds__(256) void node_kernel(
    const float* __restrict__ A, const float* __restrict__ Wmix,
    const float* __restrict__ wquad, const float* __restrict__ Wread,
    const float* __restrict__ attrs, const float* __restrict__ ae,
    const int* __restrict__ batch, const int* __restrict__ counts,
    float* __restrict__ out) {
    __shared__ float Ald[8][CC * 9];
    __shared__ float ne_s[8];
    __shared__ int g_s[8];
    const int t = threadIdx.x;
    const int ln = t >> 5;
    const int d = t & 31;
    const int n = blockIdx.x * 8 + ln;

    const float sc = (counts[n] != 0) ? (1.f / 16.f) : 0.f;
    const float* Arow = A + (size_t)n * (CC * 9);
#pragma unroll
    for (int i = 0; i < 9; ++i) Ald[ln][d + 32 * i] = Arow[d + 32 * i] * sc;
    __syncthreads();

    float A2[9];
#pragma unroll
    for (int m = 0; m < 9; ++m) {
        const int l = (m == 0) ? 0 : ((m < 4) ? 1 : 2);
        float acc = 0.f;
#pragma unroll
        for (int cch = 0; cch < CC; ++cch)
            acc = fmaf(Wmix[(l * CC + cch) * CC + d], Ald[ln][cch * 9 + m], acc);
        A2[m] = acc;
    }

    const float q0 = wquad[0], q1 = wquad[1], q2 = wquad[2];
    const float n0 = A2[0] * A2[0];
    const float n1 = A2[1] * A2[1] + A2[2] * A2[2] + A2[3] * A2[3];
    const float n2 = A2[4] * A2[4] + A2[5] * A2[5] + A2[6] * A2[6] + A2[7] * A2[7] + A2[8] * A2[8];
    const float B = A2[0] + n0 * q0 + n1 * q1 + n2 * q2;

    float v = B * Wread[d];
#pragma unroll
    for (int off = 16; off; off >>= 1) v += __shfl_xor(v, off, 32);

    if (d == 0) {
        float ne = v;
#pragma unroll
        for (int s = 0; s < NSPEC; ++s) ne += attrs[n * NSPEC + s] * ae[s];
        ne_s[ln] = ne;
        g_s[ln] = batch[n];
    }
    __syncthreads();
    if (t == 0) {
        float acc = ne_s[0];
        int g = g_s[0];
#pragma unroll
        for (int i = 1; i < 8; ++i) {
            if (g_s[i] == g) acc += ne_s[i];
            else { atomicAdd(&out[g], acc); g = g_s[i]; acc = ne_s[i]; }
        }
        atomicAdd(&out[g], acc);
    }
}

extern "C" void kernel_launch(void* const* d_in, const int* in_sizes, int n_in,
                              void* d_out, int out_size, void* d_ws, size_t ws_size,
                              hipStream_t stream) {
    const float* attrs  = (const float*)d_in[0];
    const float* pos    = (const float*)d_in[1];
    const float* shifts = (const float*)d_in[2];
    const float* Wemb   = (const float*)d_in[3];
    const float* rW1    = (const float*)d_in[4];
    const float* rb1    = (const float*)d_in[5];
    const float* rW2    = (const float*)d_in[6];
    const float* rb2    = (const float*)d_in[7];
    const float* rW3    = (const float*)d_in[8];
    const float* Wmix   = (const float*)d_in[9];
    const float* wquad  = (const float*)d_in[10];
    const float* Wread  = (const float*)d_in[11];
    const float* ae     = (const float*)d_in[12];
    const int* eidx     = (const int*)d_in[13];
    const int* batch    = (const int*)d_in[14];
    float* out = (float*)d_out;

    char* wsp = (char*)d_ws;
    float* A      = (float*)wsp;  wsp += (size_t)NNODES * CC * 9 * 4;  // 57.6 MB
    int* rank     = (int*)A;      // alias: dead after scatter; boundary rows re-zeroed AFTER
    int* perm     = (int*)wsp;    wsp += (size_t)NEDGES * 4;           // 3.2 MB
    int* offsets  = (int*)wsp;    wsp += (size_t)SCAN_N * 4;
    int* counts   = (int*)wsp;    wsp += (size_t)SCAN_N * 4;
    int* species  = (int*)wsp;    wsp += (size_t)NNODES * 4;
    __hip_bfloat16* W1T = (__hip_bfloat16*)wsp; wsp += 64 * 32 * 2;
    __hip_bfloat16* W2T = (__hip_bfloat16*)wsp; wsp += 64 * 64 * 2;
    __hip_bfloat16* W3T = (__hip_bfloat16*)wsp; wsp += 96 * 64 * 2;

    hipMemsetAsync(counts, 0, (size_t)SCAN_N * sizeof(int), stream);

    prep_hist_kernel<<<NEDGES / 256, 256, 0, stream>>>(attrs, eidx, rW1, rb1, rW2, rW3,
                                                       counts, rank, species, W1T, W2T, W3T);
    scan_kernel<<<1, 1024, 0, stream>>>(counts, offsets, out);
    scatter_kernel<<<NEDGES / 256, 256, 0, stream>>>(eidx, offsets, rank, perm);
    zero_bounds_kernel<<<NCHUNK, 576, 0, stream>>>(perm, eidx, A);

    edge_kernel<<<NCHUNK, EBLK, 0, stream>>>(pos, shifts, eidx, perm,
                                             W1T, W2T, W3T, rb2, species, Wemb, A);
    node_kernel<<<NNODES / 8, 256, 0, stream>>>(A, Wmix, wquad, Wread, attrs, ae, batch,
                                                counts, out);
}